// Round 1
// baseline (723.680 us; speedup 1.0000x reference)
//
#include <hip/hip_runtime.h>

#define N_NODES 50000
#define N_EDGES 800000
#define NEG_SLOPE 0.2f

__device__ __forceinline__ float leaky(float x) { return x >= 0.f ? x : NEG_SLOPE * x; }

// float atomic max via int punning (two-sided trick)
__device__ __forceinline__ void atomicMaxFloat(float* addr, float val) {
    if (val >= 0.f) atomicMax((int*)addr, __float_as_int(val));
    else            atomicMin((unsigned int*)addr, __float_as_uint(val));
}

// h = x @ W  (x: [n,K], W: [K,64] row-major), plus s_src = h@a_src, s_dst = h@a_dst,
// and m[i] initialized to the self-loop logit leaky(s_src[i]+s_dst[i]).
// One wave (64 lanes) per node row; lane = output dim.
template <int K>
__global__ __launch_bounds__(256) void gat_gemm_kernel(
    const float* __restrict__ x, const float* __restrict__ W,
    const float* __restrict__ a_src, const float* __restrict__ a_dst,
    float* __restrict__ h, float* __restrict__ s_src, float* __restrict__ s_dst,
    float* __restrict__ m, int n)
{
    __shared__ float Wl[K * 64];
    __shared__ float asl[64];
    __shared__ float adl[64];
    int tid = threadIdx.x;
    for (int i = tid; i < K * 64; i += 256) Wl[i] = W[i];
    if (tid < 64) { asl[tid] = a_src[tid]; adl[tid] = a_dst[tid]; }
    __syncthreads();

    int wave = tid >> 6, lane = tid & 63;
    int row = blockIdx.x * 4 + wave;
    if (row >= n) return;

    const float* xr = x + (size_t)row * K;
    float acc = 0.f;
    for (int k0 = 0; k0 < K; k0 += 64) {
        float xv = xr[k0 + lane];
        #pragma unroll
        for (int kk = 0; kk < 64; ++kk) {
            float xk = __shfl(xv, kk, 64);
            acc += xk * Wl[(k0 + kk) * 64 + lane];
        }
    }
    h[(size_t)row * 64 + lane] = acc;

    float vs = acc * asl[lane];
    float vd = acc * adl[lane];
    #pragma unroll
    for (int off = 32; off; off >>= 1) {
        vs += __shfl_xor(vs, off, 64);
        vd += __shfl_xor(vd, off, 64);
    }
    if (lane == 0) {
        s_src[row] = vs;
        s_dst[row] = vd;
        m[row] = leaky(vs + vd);   // self-loop logit seeds the segment max
    }
}

// segment max over edges: m[dst] = max(m[dst], leaky(s_src[src]+s_dst[dst]))
__global__ __launch_bounds__(256) void edge_max_kernel(
    const int* __restrict__ src, const int* __restrict__ dst,
    const float* __restrict__ s_src, const float* __restrict__ s_dst,
    float* __restrict__ m)
{
    int e = blockIdx.x * 256 + threadIdx.x;
    if (e >= N_EDGES) return;
    int s = src[e], d = dst[e];
    float logit = leaky(s_src[s] + s_dst[d]);
    atomicMaxFloat(&m[d], logit);
}

// self-loop contribution: den[i] = exp(self - m); t[i][:] = den * h[i][:]
__global__ __launch_bounds__(256) void node_init_kernel(
    const float* __restrict__ h, const float* __restrict__ s_src,
    const float* __restrict__ s_dst, const float* __restrict__ m,
    float* __restrict__ t, float* __restrict__ den, int n)
{
    int row = blockIdx.x * 4 + (threadIdx.x >> 6);
    int lane = threadIdx.x & 63;
    if (row >= n) return;
    float self = leaky(s_src[row] + s_dst[row]);
    float p = expf(self - m[row]);
    if (lane == 0) den[row] = p;
    t[(size_t)row * 64 + lane] = p * h[(size_t)row * 64 + lane];
}

// per edge: w = exp(logit - m[dst]); den[dst] += w; t[dst][:] += w * h[src][:]
__global__ __launch_bounds__(256) void edge_accum_kernel(
    const int* __restrict__ src, const int* __restrict__ dst,
    const float* __restrict__ s_src, const float* __restrict__ s_dst,
    const float* __restrict__ m, const float* __restrict__ h,
    float* __restrict__ t, float* __restrict__ den)
{
    int e = blockIdx.x * 4 + (threadIdx.x >> 6);
    int lane = threadIdx.x & 63;
    if (e >= N_EDGES) return;
    int s = src[e], d = dst[e];
    float w = expf(leaky(s_src[s] + s_dst[d]) - m[d]);
    if (lane == 0)
        __hip_atomic_fetch_add(&den[d], w, __ATOMIC_RELAXED, __HIP_MEMORY_SCOPE_AGENT);
    float hv = h[(size_t)s * 64 + lane];
    __hip_atomic_fetch_add(&t[(size_t)d * 64 + lane], w * hv,
                           __ATOMIC_RELAXED, __HIP_MEMORY_SCOPE_AGENT);
}

// out = t / den + b, optional relu
template <bool RELU>
__global__ __launch_bounds__(256) void finalize_kernel(
    const float* __restrict__ t, const float* __restrict__ den,
    const float* __restrict__ b, float* __restrict__ out, int n)
{
    int row = blockIdx.x * 4 + (threadIdx.x >> 6);
    int lane = threadIdx.x & 63;
    if (row >= n) return;
    float v = t[(size_t)row * 64 + lane] / den[row] + b[lane];
    if (RELU) v = fmaxf(v, 0.f);
    out[(size_t)row * 64 + lane] = v;
}

extern "C" void kernel_launch(void* const* d_in, const int* in_sizes, int n_in,
                              void* d_out, int out_size, void* d_ws, size_t ws_size,
                              hipStream_t stream) {
    const float* x   = (const float*)d_in[0];
    const int*   ei  = (const int*)d_in[1];
    const float* W1  = (const float*)d_in[2];
    const float* a1s = (const float*)d_in[3];
    const float* a1d = (const float*)d_in[4];
    const float* b1  = (const float*)d_in[5];
    const float* W2  = (const float*)d_in[6];
    const float* a2s = (const float*)d_in[7];
    const float* a2d = (const float*)d_in[8];
    const float* b2  = (const float*)d_in[9];
    float* out = (float*)d_out;

    const int* src = ei;
    const int* dst = ei + N_EDGES;

    float* ws   = (float*)d_ws;
    float* h    = ws;                       // N*64
    float* t    = h + (size_t)N_NODES * 64; // N*64
    float* ssrc = t + (size_t)N_NODES * 64; // N
    float* sdst = ssrc + N_NODES;           // N
    float* m    = sdst + N_NODES;           // N
    float* den  = m + N_NODES;              // N

    dim3 blk(256);
    int node_blocks = (N_NODES + 3) / 4;       // 4 waves per block, 1 node/wave
    int edge_blocks_t = (N_EDGES + 255) / 256; // 1 thread/edge
    int edge_blocks_w = (N_EDGES + 3) / 4;     // 1 wave/edge

    // ---- layer 1 ----
    gat_gemm_kernel<128><<<node_blocks, blk, 0, stream>>>(x, W1, a1s, a1d, h, ssrc, sdst, m, N_NODES);
    edge_max_kernel<<<edge_blocks_t, blk, 0, stream>>>(src, dst, ssrc, sdst, m);
    node_init_kernel<<<node_blocks, blk, 0, stream>>>(h, ssrc, sdst, m, t, den, N_NODES);
    edge_accum_kernel<<<edge_blocks_w, blk, 0, stream>>>(src, dst, ssrc, sdst, m, h, t, den);
    finalize_kernel<true><<<node_blocks, blk, 0, stream>>>(t, den, b1, out, N_NODES); // out = relu(layer1), reused as layer-2 input

    // ---- layer 2 ----
    gat_gemm_kernel<64><<<node_blocks, blk, 0, stream>>>(out, W2, a2s, a2d, h, ssrc, sdst, m, N_NODES);
    edge_max_kernel<<<edge_blocks_t, blk, 0, stream>>>(src, dst, ssrc, sdst, m);
    node_init_kernel<<<node_blocks, blk, 0, stream>>>(h, ssrc, sdst, m, t, den, N_NODES);
    edge_accum_kernel<<<edge_blocks_w, blk, 0, stream>>>(src, dst, ssrc, sdst, m, h, t, den);
    finalize_kernel<false><<<node_blocks, blk, 0, stream>>>(t, den, b2, out, N_NODES);
}

// Round 2
// 378.984 us; speedup vs baseline: 1.9095x; 1.9095x over previous
//
#include <hip/hip_runtime.h>

#define N_NODES 50000
#define N_EDGES 800000
#define NEG_SLOPE 0.2f

__device__ __forceinline__ float leaky(float x) { return x >= 0.f ? x : NEG_SLOPE * x; }

// ---------------------------------------------------------------------------
// GEMM + attention score kernel: h = x@W (W: [K,64] row-major),
// s_src = h@a_src, s_dst = h@a_dst. One wave per node row, lane = out dim.
// ---------------------------------------------------------------------------
template <int K>
__global__ __launch_bounds__(256) void gat_gemm_kernel(
    const float* __restrict__ x, const float* __restrict__ W,
    const float* __restrict__ a_src, const float* __restrict__ a_dst,
    float* __restrict__ h, float* __restrict__ s_src, float* __restrict__ s_dst,
    int n)
{
    __shared__ float Wl[K * 64];
    __shared__ float asl[64];
    __shared__ float adl[64];
    int tid = threadIdx.x;
    for (int i = tid; i < K * 64; i += 256) Wl[i] = W[i];
    if (tid < 64) { asl[tid] = a_src[tid]; adl[tid] = a_dst[tid]; }
    __syncthreads();

    int wave = tid >> 6, lane = tid & 63;
    int row = blockIdx.x * 4 + wave;
    if (row >= n) return;

    const float* xr = x + (size_t)row * K;
    float acc = 0.f;
    for (int k0 = 0; k0 < K; k0 += 64) {
        float xv = xr[k0 + lane];
        #pragma unroll
        for (int kk = 0; kk < 64; ++kk) {
            float xk = __shfl(xv, kk, 64);
            acc += xk * Wl[(k0 + kk) * 64 + lane];
        }
    }
    h[(size_t)row * 64 + lane] = acc;

    float vs = acc * asl[lane];
    float vd = acc * adl[lane];
    #pragma unroll
    for (int off = 32; off; off >>= 1) {
        vs += __shfl_xor(vs, off, 64);
        vd += __shfl_xor(vd, off, 64);
    }
    if (lane == 0) { s_src[row] = vs; s_dst[row] = vd; }
}

// ---------------------------------------------------------------------------
// CSR build: histogram -> scan -> scatter (built once, reused by both layers)
// ---------------------------------------------------------------------------
__global__ __launch_bounds__(256) void zero_counts_kernel(int* __restrict__ c, int n) {
    int i = blockIdx.x * 256 + threadIdx.x;
    if (i < n) c[i] = 0;
}

__global__ __launch_bounds__(256) void count_kernel(
    const int* __restrict__ dst, int* __restrict__ counts)
{
    int e = blockIdx.x * 256 + threadIdx.x;
    if (e >= N_EDGES) return;
    atomicAdd(&counts[dst[e]], 1);
}

// per-256-block exclusive scan; block sums to bsum
__global__ __launch_bounds__(256) void scan1_kernel(
    const int* __restrict__ counts, int* __restrict__ row_off,
    int* __restrict__ bsum, int n)
{
    __shared__ int tmp[256];
    int tid = threadIdx.x;
    int i = blockIdx.x * 256 + tid;
    int v = (i < n) ? counts[i] : 0;
    tmp[tid] = v; __syncthreads();
    for (int off = 1; off < 256; off <<= 1) {
        int add = (tid >= off) ? tmp[tid - off] : 0;
        __syncthreads();
        tmp[tid] += add;
        __syncthreads();
    }
    if (i < n) row_off[i] = tmp[tid] - v;   // exclusive
    if (tid == 255) bsum[blockIdx.x] = tmp[255];
}

// single-block exclusive scan of block sums (nb <= 256)
__global__ __launch_bounds__(256) void scan2_kernel(int* __restrict__ bsum, int nb)
{
    __shared__ int tmp[256];
    int tid = threadIdx.x;
    int v = (tid < nb) ? bsum[tid] : 0;
    tmp[tid] = v; __syncthreads();
    for (int off = 1; off < 256; off <<= 1) {
        int add = (tid >= off) ? tmp[tid - off] : 0;
        __syncthreads();
        tmp[tid] += add;
        __syncthreads();
    }
    if (tid < nb) bsum[tid] = tmp[tid] - v; // exclusive
}

__global__ __launch_bounds__(256) void scan3_kernel(
    int* __restrict__ row_off, const int* __restrict__ bsum,
    int* __restrict__ cursor, int n)
{
    int i = blockIdx.x * 256 + threadIdx.x;
    if (i < n) {
        int r = row_off[i] + bsum[blockIdx.x];
        row_off[i] = r;
        cursor[i] = r;
    }
    if (i == 0) row_off[n] = N_EDGES;
}

__global__ __launch_bounds__(256) void scatter_kernel(
    const int* __restrict__ src, const int* __restrict__ dst,
    int* __restrict__ cursor, int* __restrict__ csr_src)
{
    int e = blockIdx.x * 256 + threadIdx.x;
    if (e >= N_EDGES) return;
    int pos = atomicAdd(&cursor[dst[e]], 1);
    csr_src[pos] = src[e];
}

// ---------------------------------------------------------------------------
// Fused per-node attention kernel (gather, no atomics):
// max over incoming logits (incl. self-loop), softmax weights, weighted
// feature aggregation, /den, +bias, optional ReLU. One wave per dst node.
// ---------------------------------------------------------------------------
template <bool RELU>
__global__ __launch_bounds__(256) void gat_node_kernel(
    const int* __restrict__ row_off, const int* __restrict__ csr_src,
    const float* __restrict__ s_src, const float* __restrict__ s_dst,
    const float* __restrict__ h, const float* __restrict__ b,
    float* __restrict__ out, int n)
{
    int row = blockIdx.x * 4 + (threadIdx.x >> 6);
    int lane = threadIdx.x & 63;
    if (row >= n) return;

    int beg = row_off[row], end = row_off[row + 1];
    int deg = end - beg;
    float sd = s_dst[row];
    float self_logit = leaky(s_src[row] + sd);

    // pass A: each lane's first edge (cached for broadcast), then strided rest
    int   mysrc   = -1;
    float mylogit = -INFINITY;
    if (beg + lane < end) {
        mysrc = csr_src[beg + lane];
        mylogit = leaky(s_src[mysrc] + sd);
    }
    float mx = fmaxf(self_logit, mylogit);
    for (int e = beg + 64 + lane; e < end; e += 64) {
        int s = csr_src[e];
        mx = fmaxf(mx, leaky(s_src[s] + sd));
    }
    #pragma unroll
    for (int off = 32; off; off >>= 1)
        mx = fmaxf(mx, __shfl_xor(mx, off, 64));

    // pass B: accumulate (den redundant per lane; one coalesced h-row per edge)
    float den = __expf(self_logit - mx);
    float acc = den * h[(size_t)row * 64 + lane];

    int d0 = deg < 64 ? deg : 64;
    for (int i = 0; i < d0; ++i) {
        float w = __expf(__shfl(mylogit, i, 64) - mx);
        int s = __shfl(mysrc, i, 64);
        den += w;
        acc += w * h[(size_t)s * 64 + lane];
    }
    for (int e = beg + 64; e < end; ++e) {  // rare: deg > 64
        int s = csr_src[e];
        float w = __expf(leaky(s_src[s] + sd) - mx);
        den += w;
        acc += w * h[(size_t)s * 64 + lane];
    }

    float v = acc / den + b[lane];
    if (RELU) v = fmaxf(v, 0.f);
    out[(size_t)row * 64 + lane] = v;
}

// ---------------------------------------------------------------------------
extern "C" void kernel_launch(void* const* d_in, const int* in_sizes, int n_in,
                              void* d_out, int out_size, void* d_ws, size_t ws_size,
                              hipStream_t stream) {
    const float* x   = (const float*)d_in[0];
    const int*   ei  = (const int*)d_in[1];
    const float* W1  = (const float*)d_in[2];
    const float* a1s = (const float*)d_in[3];
    const float* a1d = (const float*)d_in[4];
    const float* b1  = (const float*)d_in[5];
    const float* W2  = (const float*)d_in[6];
    const float* a2s = (const float*)d_in[7];
    const float* a2d = (const float*)d_in[8];
    const float* b2  = (const float*)d_in[9];
    float* out = (float*)d_out;

    const int* src = ei;
    const int* dst = ei + N_EDGES;

    // workspace layout
    char* p = (char*)d_ws;
    float* h    = (float*)p;            p += (size_t)N_NODES * 64 * 4;
    float* ssrc = (float*)p;            p += (size_t)N_NODES * 4;
    float* sdst = (float*)p;            p += (size_t)N_NODES * 4;
    int* row_off = (int*)p;             p += (size_t)(N_NODES + 1) * 4;
    int* cursor  = (int*)p;             p += (size_t)N_NODES * 4;
    int* bsum    = (int*)p;             p += 256 * 4;
    int* csr_src = (int*)p;             p += (size_t)N_EDGES * 4;

    dim3 blk(256);
    int node_blocks   = (N_NODES + 3) / 4;
    int node_blocks_t = (N_NODES + 255) / 256;
    int edge_blocks_t = (N_EDGES + 255) / 256;
    int scan_blocks   = (N_NODES + 255) / 256;   // 196

    // ---- CSR build (once; reused by both layers) ----
    zero_counts_kernel<<<node_blocks_t, blk, 0, stream>>>(cursor, N_NODES); // cursor doubles as counts
    count_kernel<<<edge_blocks_t, blk, 0, stream>>>(dst, cursor);
    scan1_kernel<<<scan_blocks, blk, 0, stream>>>(cursor, row_off, bsum, N_NODES);
    scan2_kernel<<<1, blk, 0, stream>>>(bsum, scan_blocks);
    scan3_kernel<<<scan_blocks, blk, 0, stream>>>(row_off, bsum, cursor, N_NODES);
    scatter_kernel<<<edge_blocks_t, blk, 0, stream>>>(src, dst, cursor, csr_src);

    // ---- layer 1 ----
    gat_gemm_kernel<128><<<node_blocks, blk, 0, stream>>>(x, W1, a1s, a1d, h, ssrc, sdst, N_NODES);
    gat_node_kernel<true><<<node_blocks, blk, 0, stream>>>(row_off, csr_src, ssrc, sdst, h, b1, out, N_NODES);

    // ---- layer 2 ----
    gat_gemm_kernel<64><<<node_blocks, blk, 0, stream>>>(out, W2, a2s, a2d, h, ssrc, sdst, N_NODES);
    gat_node_kernel<false><<<node_blocks, blk, 0, stream>>>(row_off, csr_src, ssrc, sdst, h, b2, out, N_NODES);
}

// Round 3
// 251.537 us; speedup vs baseline: 2.8770x; 1.5067x over previous
//
#include <hip/hip_runtime.h>

#define N_NODES 50000
#define N_EDGES 800000
#define NEG_SLOPE 0.2f

__device__ __forceinline__ float leaky(float x) { return x >= 0.f ? x : NEG_SLOPE * x; }

// ---------------------------------------------------------------------------
// Register-tiled GEMM + attention scores: h = x@W (W: [K,64] row-major),
// s_src = h@a_src, s_dst = h@a_dst.
// Block tile: 64 rows x 64 cols, BK=32. 256 threads; thread (tx,ty) computes
// rows ty*4..ty*4+3, cols tx*4..tx*4+3 (4x4 in registers).
// ---------------------------------------------------------------------------
template <int K>
__global__ __launch_bounds__(256) void gat_gemm_kernel(
    const float* __restrict__ x, const float* __restrict__ W,
    const float* __restrict__ a_src, const float* __restrict__ a_dst,
    float* __restrict__ h, float* __restrict__ s_src, float* __restrict__ s_dst,
    int n)
{
    constexpr int BK = 32;
    __shared__ float Wl[BK][64];   // current W chunk
    __shared__ float xt[BK][68];   // transposed x tile (pad: stride 68 -> 16B aligned, banks spread)
    __shared__ float asl[64], adl[64];

    int tid = threadIdx.x;
    if (tid < 64) { asl[tid] = a_src[tid]; adl[tid] = a_dst[tid]; }
    int tx = tid & 15, ty = tid >> 4;
    int row0 = blockIdx.x * 64;

    float acc[4][4] = {};

    for (int k0 = 0; k0 < K; k0 += BK) {
        __syncthreads();
        // stage W chunk [BK][64] linearly (contiguous b128 writes, conflict-free)
        {
            const float4* Wg = (const float4*)&W[(size_t)k0 * 64];
            float4* Ws = (float4*)&Wl[0][0];
            Ws[tid]       = Wg[tid];
            Ws[tid + 256] = Wg[tid + 256];
        }
        // stage x tile transposed: xt[k][row]
        #pragma unroll
        for (int it = 0; it < 2; ++it) {
            int idx = tid + it * 256;
            int r = idx >> 3, kq = idx & 7;       // r: 0..63, kq: 0..7
            int grow = row0 + r;
            float4 v = (grow < n) ? *(const float4*)&x[(size_t)grow * K + k0 + kq * 4]
                                  : make_float4(0.f, 0.f, 0.f, 0.f);
            xt[kq * 4 + 0][r] = v.x;
            xt[kq * 4 + 1][r] = v.y;
            xt[kq * 4 + 2][r] = v.z;
            xt[kq * 4 + 3][r] = v.w;
        }
        __syncthreads();

        #pragma unroll
        for (int kk = 0; kk < BK; ++kk) {
            float4 wv = *(const float4*)&Wl[kk][tx * 4];
            float4 xv = *(const float4*)&xt[kk][ty * 4];
            acc[0][0] += xv.x * wv.x; acc[0][1] += xv.x * wv.y; acc[0][2] += xv.x * wv.z; acc[0][3] += xv.x * wv.w;
            acc[1][0] += xv.y * wv.x; acc[1][1] += xv.y * wv.y; acc[1][2] += xv.y * wv.z; acc[1][3] += xv.y * wv.w;
            acc[2][0] += xv.z * wv.x; acc[2][1] += xv.z * wv.y; acc[2][2] += xv.z * wv.z; acc[2][3] += xv.z * wv.w;
            acc[3][0] += xv.w * wv.x; acc[3][1] += xv.w * wv.y; acc[3][2] += xv.w * wv.z; acc[3][3] += xv.w * wv.w;
        }
    }

    // epilogue: write h rows, reduce attention scores across the 16 tx lanes
    #pragma unroll
    for (int i = 0; i < 4; ++i) {
        int grow = row0 + ty * 4 + i;
        if (grow < n) {
            float4 o = make_float4(acc[i][0], acc[i][1], acc[i][2], acc[i][3]);
            *(float4*)&h[(size_t)grow * 64 + tx * 4] = o;
        }
        float s1 = acc[i][0] * asl[tx*4+0] + acc[i][1] * asl[tx*4+1]
                 + acc[i][2] * asl[tx*4+2] + acc[i][3] * asl[tx*4+3];
        float s2 = acc[i][0] * adl[tx*4+0] + acc[i][1] * adl[tx*4+1]
                 + acc[i][2] * adl[tx*4+2] + acc[i][3] * adl[tx*4+3];
        #pragma unroll
        for (int m = 1; m < 16; m <<= 1) {
            s1 += __shfl_xor(s1, m, 64);
            s2 += __shfl_xor(s2, m, 64);
        }
        if (tx == 0 && grow < n) { s_src[grow] = s1; s_dst[grow] = s2; }
    }
}

// ---------------------------------------------------------------------------
// CSR build: histogram -> scan -> scatter (built once, reused by both layers)
// ---------------------------------------------------------------------------
__global__ __launch_bounds__(256) void zero_counts_kernel(int* __restrict__ c, int n) {
    int i = blockIdx.x * 256 + threadIdx.x;
    if (i < n) c[i] = 0;
}

__global__ __launch_bounds__(256) void count_kernel(
    const int* __restrict__ dst, int* __restrict__ counts)
{
    int e = blockIdx.x * 256 + threadIdx.x;
    if (e >= N_EDGES) return;
    atomicAdd(&counts[dst[e]], 1);
}

__global__ __launch_bounds__(256) void scan1_kernel(
    const int* __restrict__ counts, int* __restrict__ row_off,
    int* __restrict__ bsum, int n)
{
    __shared__ int tmp[256];
    int tid = threadIdx.x;
    int i = blockIdx.x * 256 + tid;
    int v = (i < n) ? counts[i] : 0;
    tmp[tid] = v; __syncthreads();
    for (int off = 1; off < 256; off <<= 1) {
        int add = (tid >= off) ? tmp[tid - off] : 0;
        __syncthreads();
        tmp[tid] += add;
        __syncthreads();
    }
    if (i < n) row_off[i] = tmp[tid] - v;   // exclusive
    if (tid == 255) bsum[blockIdx.x] = tmp[255];
}

__global__ __launch_bounds__(256) void scan2_kernel(int* __restrict__ bsum, int nb)
{
    __shared__ int tmp[256];
    int tid = threadIdx.x;
    int v = (tid < nb) ? bsum[tid] : 0;
    tmp[tid] = v; __syncthreads();
    for (int off = 1; off < 256; off <<= 1) {
        int add = (tid >= off) ? tmp[tid - off] : 0;
        __syncthreads();
        tmp[tid] += add;
        __syncthreads();
    }
    if (tid < nb) bsum[tid] = tmp[tid] - v; // exclusive
}

__global__ __launch_bounds__(256) void scan3_kernel(
    int* __restrict__ row_off, const int* __restrict__ bsum,
    int* __restrict__ cursor, int n)
{
    int i = blockIdx.x * 256 + threadIdx.x;
    if (i < n) {
        int r = row_off[i] + bsum[blockIdx.x];
        row_off[i] = r;
        cursor[i] = r;
    }
    if (i == 0) row_off[n] = N_EDGES;
}

__global__ __launch_bounds__(256) void scatter_kernel(
    const int* __restrict__ src, const int* __restrict__ dst,
    int* __restrict__ cursor, int* __restrict__ csr_src)
{
    int e = blockIdx.x * 256 + threadIdx.x;
    if (e >= N_EDGES) return;
    int pos = atomicAdd(&cursor[dst[e]], 1);
    csr_src[pos] = src[e];
}

// ---------------------------------------------------------------------------
// Fused per-node attention kernel (gather, no atomics). One wave per dst node.
// ---------------------------------------------------------------------------
template <bool RELU>
__global__ __launch_bounds__(256) void gat_node_kernel(
    const int* __restrict__ row_off, const int* __restrict__ csr_src,
    const float* __restrict__ s_src, const float* __restrict__ s_dst,
    const float* __restrict__ h, const float* __restrict__ b,
    float* __restrict__ out, int n)
{
    int row = blockIdx.x * 4 + (threadIdx.x >> 6);
    int lane = threadIdx.x & 63;
    if (row >= n) return;

    int beg = row_off[row], end = row_off[row + 1];
    int deg = end - beg;
    float sd = s_dst[row];
    float self_logit = leaky(s_src[row] + sd);

    // pass A: max over incoming logits (incl. self)
    int   mysrc   = -1;
    float mylogit = -INFINITY;
    if (beg + lane < end) {
        mysrc = csr_src[beg + lane];
        mylogit = leaky(s_src[mysrc] + sd);
    }
    float mx = fmaxf(self_logit, mylogit);
    for (int e = beg + 64 + lane; e < end; e += 64) {
        int s = csr_src[e];
        mx = fmaxf(mx, leaky(s_src[s] + sd));
    }
    #pragma unroll
    for (int off = 32; off; off >>= 1)
        mx = fmaxf(mx, __shfl_xor(mx, off, 64));

    // pass B: accumulate
    float den = __expf(self_logit - mx);
    float acc = den * h[(size_t)row * 64 + lane];

    int d0 = deg < 64 ? deg : 64;
    for (int i = 0; i < d0; ++i) {
        float w = __expf(__shfl(mylogit, i, 64) - mx);
        int s = __shfl(mysrc, i, 64);
        den += w;
        acc += w * h[(size_t)s * 64 + lane];
    }
    for (int e = beg + 64; e < end; ++e) {  // rare: deg > 64
        int s = csr_src[e];
        float w = __expf(leaky(s_src[s] + sd) - mx);
        den += w;
        acc += w * h[(size_t)s * 64 + lane];
    }

    float v = acc / den + b[lane];
    if (RELU) v = fmaxf(v, 0.f);
    out[(size_t)row * 64 + lane] = v;
}

// ---------------------------------------------------------------------------
extern "C" void kernel_launch(void* const* d_in, const int* in_sizes, int n_in,
                              void* d_out, int out_size, void* d_ws, size_t ws_size,
                              hipStream_t stream) {
    const float* x   = (const float*)d_in[0];
    const int*   ei  = (const int*)d_in[1];
    const float* W1  = (const float*)d_in[2];
    const float* a1s = (const float*)d_in[3];
    const float* a1d = (const float*)d_in[4];
    const float* b1  = (const float*)d_in[5];
    const float* W2  = (const float*)d_in[6];
    const float* a2s = (const float*)d_in[7];
    const float* a2d = (const float*)d_in[8];
    const float* b2  = (const float*)d_in[9];
    float* out = (float*)d_out;

    const int* src = ei;
    const int* dst = ei + N_EDGES;

    // workspace layout
    char* p = (char*)d_ws;
    float* h    = (float*)p;            p += (size_t)N_NODES * 64 * 4;
    float* ssrc = (float*)p;            p += (size_t)N_NODES * 4;
    float* sdst = (float*)p;            p += (size_t)N_NODES * 4;
    int* row_off = (int*)p;             p += (size_t)(N_NODES + 1) * 4;
    int* cursor  = (int*)p;             p += (size_t)N_NODES * 4;
    int* bsum    = (int*)p;             p += 256 * 4;
    int* csr_src = (int*)p;             p += (size_t)N_EDGES * 4;

    dim3 blk(256);
    int gemm_blocks   = (N_NODES + 63) / 64;
    int node_blocks   = (N_NODES + 3) / 4;
    int node_blocks_t = (N_NODES + 255) / 256;
    int edge_blocks_t = (N_EDGES + 255) / 256;
    int scan_blocks   = (N_NODES + 255) / 256;

    // ---- CSR build (once; reused by both layers) ----
    zero_counts_kernel<<<node_blocks_t, blk, 0, stream>>>(cursor, N_NODES);
    count_kernel<<<edge_blocks_t, blk, 0, stream>>>(dst, cursor);
    scan1_kernel<<<scan_blocks, blk, 0, stream>>>(cursor, row_off, bsum, N_NODES);
    scan2_kernel<<<1, blk, 0, stream>>>(bsum, scan_blocks);
    scan3_kernel<<<scan_blocks, blk, 0, stream>>>(row_off, bsum, cursor, N_NODES);
    scatter_kernel<<<edge_blocks_t, blk, 0, stream>>>(src, dst, cursor, csr_src);

    // ---- layer 1 ----
    gat_gemm_kernel<128><<<gemm_blocks, blk, 0, stream>>>(x, W1, a1s, a1d, h, ssrc, sdst, N_NODES);
    gat_node_kernel<true><<<node_blocks, blk, 0, stream>>>(row_off, csr_src, ssrc, sdst, h, b1, out, N_NODES);

    // ---- layer 2 ----
    gat_gemm_kernel<64><<<gemm_blocks, blk, 0, stream>>>(out, W2, a2s, a2d, h, ssrc, sdst, N_NODES);
    gat_node_kernel<false><<<node_blocks, blk, 0, stream>>>(row_off, csr_src, ssrc, sdst, h, b2, out, N_NODES);
}

// Round 4
// 249.865 us; speedup vs baseline: 2.8963x; 1.0067x over previous
//
#include <hip/hip_runtime.h>

#define N_NODES 50000
#define N_EDGES 800000
#define NEG_SLOPE 0.2f

__device__ __forceinline__ float leaky(float x) { return x >= 0.f ? x : NEG_SLOPE * x; }
__device__ __forceinline__ float readlane_f(float v, int i) {
    return __uint_as_float(__builtin_amdgcn_readlane(__float_as_uint(v), i));
}

// ---------------------------------------------------------------------------
// Register-tiled GEMM + attention scores: h = x@W (W: [K,64] row-major),
// s_src = h@a_src, s_dst = h@a_dst.  64x64 tile, BK=32, 4x4 per thread.
// ---------------------------------------------------------------------------
template <int K>
__global__ __launch_bounds__(256) void gat_gemm_kernel(
    const float* __restrict__ x, const float* __restrict__ W,
    const float* __restrict__ a_src, const float* __restrict__ a_dst,
    float* __restrict__ h, float* __restrict__ s_src, float* __restrict__ s_dst,
    int n)
{
    constexpr int BK = 32;
    __shared__ float Wl[BK][64];
    __shared__ float xt[BK][68];
    __shared__ float asl[64], adl[64];

    int tid = threadIdx.x;
    if (tid < 64) { asl[tid] = a_src[tid]; adl[tid] = a_dst[tid]; }
    int tx = tid & 15, ty = tid >> 4;
    int row0 = blockIdx.x * 64;

    float acc[4][4] = {};

    for (int k0 = 0; k0 < K; k0 += BK) {
        __syncthreads();
        {
            const float4* Wg = (const float4*)&W[(size_t)k0 * 64];
            float4* Ws = (float4*)&Wl[0][0];
            Ws[tid]       = Wg[tid];
            Ws[tid + 256] = Wg[tid + 256];
        }
        #pragma unroll
        for (int it = 0; it < 2; ++it) {
            int idx = tid + it * 256;
            int r = idx >> 3, kq = idx & 7;
            int grow = row0 + r;
            float4 v = (grow < n) ? *(const float4*)&x[(size_t)grow * K + k0 + kq * 4]
                                  : make_float4(0.f, 0.f, 0.f, 0.f);
            xt[kq * 4 + 0][r] = v.x;
            xt[kq * 4 + 1][r] = v.y;
            xt[kq * 4 + 2][r] = v.z;
            xt[kq * 4 + 3][r] = v.w;
        }
        __syncthreads();

        #pragma unroll
        for (int kk = 0; kk < BK; ++kk) {
            float4 wv = *(const float4*)&Wl[kk][tx * 4];
            float4 xv = *(const float4*)&xt[kk][ty * 4];
            acc[0][0] += xv.x * wv.x; acc[0][1] += xv.x * wv.y; acc[0][2] += xv.x * wv.z; acc[0][3] += xv.x * wv.w;
            acc[1][0] += xv.y * wv.x; acc[1][1] += xv.y * wv.y; acc[1][2] += xv.y * wv.z; acc[1][3] += xv.y * wv.w;
            acc[2][0] += xv.z * wv.x; acc[2][1] += xv.z * wv.y; acc[2][2] += xv.z * wv.z; acc[2][3] += xv.z * wv.w;
            acc[3][0] += xv.w * wv.x; acc[3][1] += xv.w * wv.y; acc[3][2] += xv.w * wv.z; acc[3][3] += xv.w * wv.w;
        }
    }

    #pragma unroll
    for (int i = 0; i < 4; ++i) {
        int grow = row0 + ty * 4 + i;
        if (grow < n) {
            float4 o = make_float4(acc[i][0], acc[i][1], acc[i][2], acc[i][3]);
            *(float4*)&h[(size_t)grow * 64 + tx * 4] = o;
        }
        float s1 = acc[i][0] * asl[tx*4+0] + acc[i][1] * asl[tx*4+1]
                 + acc[i][2] * asl[tx*4+2] + acc[i][3] * asl[tx*4+3];
        float s2 = acc[i][0] * adl[tx*4+0] + acc[i][1] * adl[tx*4+1]
                 + acc[i][2] * adl[tx*4+2] + acc[i][3] * adl[tx*4+3];
        #pragma unroll
        for (int m = 1; m < 16; m <<= 1) {
            s1 += __shfl_xor(s1, m, 64);
            s2 += __shfl_xor(s2, m, 64);
        }
        if (tx == 0 && grow < n) { s_src[grow] = s1; s_dst[grow] = s2; }
    }
}

// ---------------------------------------------------------------------------
// CSR build: histogram -> scan -> scatter
// ---------------------------------------------------------------------------
__global__ __launch_bounds__(256) void zero_counts_kernel(int* __restrict__ c, int n) {
    int i = blockIdx.x * 256 + threadIdx.x;
    if (i < n) c[i] = 0;
}

__global__ __launch_bounds__(256) void count_kernel(
    const int* __restrict__ dst, int* __restrict__ counts)
{
    int e = blockIdx.x * 256 + threadIdx.x;
    if (e >= N_EDGES) return;
    atomicAdd(&counts[dst[e]], 1);
}

__global__ __launch_bounds__(256) void scan1_kernel(
    const int* __restrict__ counts, int* __restrict__ row_off,
    int* __restrict__ bsum, int n)
{
    __shared__ int tmp[256];
    int tid = threadIdx.x;
    int i = blockIdx.x * 256 + tid;
    int v = (i < n) ? counts[i] : 0;
    tmp[tid] = v; __syncthreads();
    for (int off = 1; off < 256; off <<= 1) {
        int add = (tid >= off) ? tmp[tid - off] : 0;
        __syncthreads();
        tmp[tid] += add;
        __syncthreads();
    }
    if (i < n) row_off[i] = tmp[tid] - v;
    if (tid == 255) bsum[blockIdx.x] = tmp[255];
}

__global__ __launch_bounds__(256) void scan2_kernel(int* __restrict__ bsum, int nb)
{
    __shared__ int tmp[256];
    int tid = threadIdx.x;
    int v = (tid < nb) ? bsum[tid] : 0;
    tmp[tid] = v; __syncthreads();
    for (int off = 1; off < 256; off <<= 1) {
        int add = (tid >= off) ? tmp[tid - off] : 0;
        __syncthreads();
        tmp[tid] += add;
        __syncthreads();
    }
    if (tid < nb) bsum[tid] = tmp[tid] - v;
}

__global__ __launch_bounds__(256) void scan3_kernel(
    int* __restrict__ row_off, const int* __restrict__ bsum,
    int* __restrict__ cursor, int n)
{
    int i = blockIdx.x * 256 + threadIdx.x;
    if (i < n) {
        int r = row_off[i] + bsum[blockIdx.x];
        row_off[i] = r;
        cursor[i] = r;
    }
    if (i == 0) row_off[n] = N_EDGES;
}

__global__ __launch_bounds__(256) void scatter_kernel(
    const int* __restrict__ src, const int* __restrict__ dst,
    int* __restrict__ cursor, int* __restrict__ csr_src)
{
    int e = blockIdx.x * 256 + threadIdx.x;
    if (e >= N_EDGES) return;
    int pos = atomicAdd(&cursor[dst[e]], 1);
    csr_src[pos] = src[e];
}

// ---------------------------------------------------------------------------
// Fused per-node attention kernel. One wave per dst node.
// Pass B uses readlane broadcasts (SGPR) + vectorized exp, no bpermute.
// ---------------------------------------------------------------------------
template <bool RELU>
__global__ __launch_bounds__(256) void gat_node_kernel(
    const int* __restrict__ row_off, const int* __restrict__ csr_src,
    const float* __restrict__ s_src, const float* __restrict__ s_dst,
    const float* __restrict__ h, const float* __restrict__ b,
    float* __restrict__ out, int n)
{
    int row = blockIdx.x * 4 + (threadIdx.x >> 6);
    int lane = threadIdx.x & 63;
    if (row >= n) return;

    int beg = row_off[row], end = row_off[row + 1];
    int deg = end - beg;
    float sd = s_dst[row];
    float self_logit = leaky(s_src[row] + sd);

    // self h row: issue early
    float hself = h[(size_t)row * 64 + lane];

    // pass A: per-lane edge + strided tail -> wave max
    int   mysrc   = 0;
    float mylogit = -INFINITY;
    if (lane < deg) {
        mysrc = csr_src[beg + lane];
        mylogit = leaky(s_src[mysrc] + sd);
    }
    float mx = fmaxf(self_logit, mylogit);
    for (int e = beg + 64 + lane; e < end; e += 64) {
        int s = csr_src[e];
        mx = fmaxf(mx, leaky(s_src[s] + sd));
    }
    #pragma unroll
    for (int off = 32; off; off >>= 1)
        mx = fmaxf(mx, __shfl_xor(mx, off, 64));

    // vectorized weights: ONE v_exp covers the wave's 64 edges
    float w64 = __expf(mylogit - mx);           // invalid lanes -> exp(-inf) = 0
    float den = w64;
    #pragma unroll
    for (int off = 32; off; off >>= 1)
        den += __shfl_xor(den, off, 64);
    float wself = __expf(self_logit - mx);
    den += wself;

    float acc = wself * hself;

    // pass B: serial over edges, SGPR broadcasts, pipelined gathers
    int d0 = deg < 64 ? deg : 64;
    #pragma unroll 4
    for (int i = 0; i < d0; ++i) {
        int   s = __builtin_amdgcn_readlane(mysrc, i);
        float w = readlane_f(w64, i);
        acc += w * h[(size_t)s * 64 + lane];
    }
    // rare tail: deg > 64
    for (int e = beg + 64; e < end; ++e) {
        int s = csr_src[e];
        float w = __expf(leaky(s_src[s] + sd) - mx);
        den += w;
        acc += w * h[(size_t)s * 64 + lane];
    }

    float v = acc / den + b[lane];
    if (RELU) v = fmaxf(v, 0.f);
    out[(size_t)row * 64 + lane] = v;
}

// ---------------------------------------------------------------------------
extern "C" void kernel_launch(void* const* d_in, const int* in_sizes, int n_in,
                              void* d_out, int out_size, void* d_ws, size_t ws_size,
                              hipStream_t stream) {
    const float* x   = (const float*)d_in[0];
    const int*   ei  = (const int*)d_in[1];
    const float* W1  = (const float*)d_in[2];
    const float* a1s = (const float*)d_in[3];
    const float* a1d = (const float*)d_in[4];
    const float* b1  = (const float*)d_in[5];
    const float* W2  = (const float*)d_in[6];
    const float* a2s = (const float*)d_in[7];
    const float* a2d = (const float*)d_in[8];
    const float* b2  = (const float*)d_in[9];
    float* out = (float*)d_out;

    const int* src = ei;
    const int* dst = ei + N_EDGES;

    char* p = (char*)d_ws;
    float* h    = (float*)p;            p += (size_t)N_NODES * 64 * 4;
    float* ssrc = (float*)p;            p += (size_t)N_NODES * 4;
    float* sdst = (float*)p;            p += (size_t)N_NODES * 4;
    int* row_off = (int*)p;             p += (size_t)(N_NODES + 1) * 4;
    int* cursor  = (int*)p;             p += (size_t)N_NODES * 4;
    int* bsum    = (int*)p;             p += 256 * 4;
    int* csr_src = (int*)p;             p += (size_t)N_EDGES * 4;

    dim3 blk(256);
    int gemm_blocks   = (N_NODES + 63) / 64;
    int node_blocks   = (N_NODES + 3) / 4;
    int node_blocks_t = (N_NODES + 255) / 256;
    int edge_blocks_t = (N_EDGES + 255) / 256;
    int scan_blocks   = (N_NODES + 255) / 256;

    // ---- CSR build ----
    zero_counts_kernel<<<node_blocks_t, blk, 0, stream>>>(cursor, N_NODES);
    count_kernel<<<edge_blocks_t, blk, 0, stream>>>(dst, cursor);
    scan1_kernel<<<scan_blocks, blk, 0, stream>>>(cursor, row_off, bsum, N_NODES);
    scan2_kernel<<<1, blk, 0, stream>>>(bsum, scan_blocks);
    scan3_kernel<<<scan_blocks, blk, 0, stream>>>(row_off, bsum, cursor, N_NODES);
    scatter_kernel<<<edge_blocks_t, blk, 0, stream>>>(src, dst, cursor, csr_src);

    // ---- layer 1 ----
    gat_gemm_kernel<128><<<gemm_blocks, blk, 0, stream>>>(x, W1, a1s, a1d, h, ssrc, sdst, N_NODES);
    gat_node_kernel<true><<<node_blocks, blk, 0, stream>>>(row_off, csr_src, ssrc, sdst, h, b1, out, N_NODES);

    // ---- layer 2 ----
    gat_gemm_kernel<64><<<gemm_blocks, blk, 0, stream>>>(out, W2, a2s, a2d, h, ssrc, sdst, N_NODES);
    gat_node_kernel<false><<<node_blocks, blk, 0, stream>>>(row_off, csr_src, ssrc, sdst, h, b2, out, N_NODES);
}

// Round 5
// 209.552 us; speedup vs baseline: 3.4535x; 1.1924x over previous
//
#include <hip/hip_runtime.h>

#define N_NODES 50000
#define N_EDGES 800000
#define NEG_SLOPE 0.2f

__device__ __forceinline__ float leaky(float x) { return x >= 0.f ? x : NEG_SLOPE * x; }
__device__ __forceinline__ float readlane_f(float v, int i) {
    return __uint_as_float(__builtin_amdgcn_readlane(__float_as_uint(v), i));
}

// ---------------------------------------------------------------------------
// Register-tiled GEMM + attention scores: h = x@W (W: [K,64] row-major),
// s_src = h@a_src, s_dst = h@a_dst.  64x64 tile, BK=32, 4x4 per thread.
// ---------------------------------------------------------------------------
template <int K>
__global__ __launch_bounds__(256) void gat_gemm_kernel(
    const float* __restrict__ x, const float* __restrict__ W,
    const float* __restrict__ a_src, const float* __restrict__ a_dst,
    float* __restrict__ h, float* __restrict__ s_src, float* __restrict__ s_dst,
    int n)
{
    constexpr int BK = 32;
    __shared__ float Wl[BK][64];
    __shared__ float xt[BK][68];
    __shared__ float asl[64], adl[64];

    int tid = threadIdx.x;
    if (tid < 64) { asl[tid] = a_src[tid]; adl[tid] = a_dst[tid]; }
    int tx = tid & 15, ty = tid >> 4;
    int row0 = blockIdx.x * 64;

    float acc[4][4] = {};

    for (int k0 = 0; k0 < K; k0 += BK) {
        __syncthreads();
        {
            const float4* Wg = (const float4*)&W[(size_t)k0 * 64];
            float4* Ws = (float4*)&Wl[0][0];
            Ws[tid]       = Wg[tid];
            Ws[tid + 256] = Wg[tid + 256];
        }
        #pragma unroll
        for (int it = 0; it < 2; ++it) {
            int idx = tid + it * 256;
            int r = idx >> 3, kq = idx & 7;
            int grow = row0 + r;
            float4 v = (grow < n) ? *(const float4*)&x[(size_t)grow * K + k0 + kq * 4]
                                  : make_float4(0.f, 0.f, 0.f, 0.f);
            xt[kq * 4 + 0][r] = v.x;
            xt[kq * 4 + 1][r] = v.y;
            xt[kq * 4 + 2][r] = v.z;
            xt[kq * 4 + 3][r] = v.w;
        }
        __syncthreads();

        #pragma unroll
        for (int kk = 0; kk < BK; ++kk) {
            float4 wv = *(const float4*)&Wl[kk][tx * 4];
            float4 xv = *(const float4*)&xt[kk][ty * 4];
            acc[0][0] += xv.x * wv.x; acc[0][1] += xv.x * wv.y; acc[0][2] += xv.x * wv.z; acc[0][3] += xv.x * wv.w;
            acc[1][0] += xv.y * wv.x; acc[1][1] += xv.y * wv.y; acc[1][2] += xv.y * wv.z; acc[1][3] += xv.y * wv.w;
            acc[2][0] += xv.z * wv.x; acc[2][1] += xv.z * wv.y; acc[2][2] += xv.z * wv.z; acc[2][3] += xv.z * wv.w;
            acc[3][0] += xv.w * wv.x; acc[3][1] += xv.w * wv.y; acc[3][2] += xv.w * wv.z; acc[3][3] += xv.w * wv.w;
        }
    }

    #pragma unroll
    for (int i = 0; i < 4; ++i) {
        int grow = row0 + ty * 4 + i;
        if (grow < n) {
            float4 o = make_float4(acc[i][0], acc[i][1], acc[i][2], acc[i][3]);
            *(float4*)&h[(size_t)grow * 64 + tx * 4] = o;
        }
        float s1 = acc[i][0] * asl[tx*4+0] + acc[i][1] * asl[tx*4+1]
                 + acc[i][2] * asl[tx*4+2] + acc[i][3] * asl[tx*4+3];
        float s2 = acc[i][0] * adl[tx*4+0] + acc[i][1] * adl[tx*4+1]
                 + acc[i][2] * adl[tx*4+2] + acc[i][3] * adl[tx*4+3];
        #pragma unroll
        for (int m = 1; m < 16; m <<= 1) {
            s1 += __shfl_xor(s1, m, 64);
            s2 += __shfl_xor(s2, m, 64);
        }
        if (tx == 0 && grow < n) { s_src[grow] = s1; s_dst[grow] = s2; }
    }
}

// ---------------------------------------------------------------------------
// CSR build: histogram -> scan -> scatter
// ---------------------------------------------------------------------------
__global__ __launch_bounds__(256) void count_kernel(
    const int* __restrict__ dst, int* __restrict__ counts)
{
    int e = blockIdx.x * 256 + threadIdx.x;
    if (e >= N_EDGES) return;
    atomicAdd(&counts[dst[e]], 1);
}

__global__ __launch_bounds__(256) void scan1_kernel(
    const int* __restrict__ counts, int* __restrict__ row_off,
    int* __restrict__ bsum, int n)
{
    __shared__ int tmp[256];
    int tid = threadIdx.x;
    int i = blockIdx.x * 256 + tid;
    int v = (i < n) ? counts[i] : 0;
    tmp[tid] = v; __syncthreads();
    for (int off = 1; off < 256; off <<= 1) {
        int add = (tid >= off) ? tmp[tid - off] : 0;
        __syncthreads();
        tmp[tid] += add;
        __syncthreads();
    }
    if (i < n) row_off[i] = tmp[tid] - v;
    if (tid == 255) bsum[blockIdx.x] = tmp[255];
}

__global__ __launch_bounds__(256) void scan2_kernel(int* __restrict__ bsum, int nb)
{
    __shared__ int tmp[256];
    int tid = threadIdx.x;
    int v = (tid < nb) ? bsum[tid] : 0;
    tmp[tid] = v; __syncthreads();
    for (int off = 1; off < 256; off <<= 1) {
        int add = (tid >= off) ? tmp[tid - off] : 0;
        __syncthreads();
        tmp[tid] += add;
        __syncthreads();
    }
    if (tid < nb) bsum[tid] = tmp[tid] - v;
}

__global__ __launch_bounds__(256) void scan3_kernel(
    int* __restrict__ row_off, const int* __restrict__ bsum,
    int* __restrict__ cursor, int n)
{
    int i = blockIdx.x * 256 + threadIdx.x;
    if (i < n) {
        int r = row_off[i] + bsum[blockIdx.x];
        row_off[i] = r;
        cursor[i] = r;
    }
    if (i == 0) row_off[n] = N_EDGES;
}

__global__ __launch_bounds__(256) void scatter_kernel(
    const int* __restrict__ src, const int* __restrict__ dst,
    int* __restrict__ cursor, int* __restrict__ csr_src)
{
    int e = blockIdx.x * 256 + threadIdx.x;
    if (e >= N_EDGES) return;
    int pos = atomicAdd(&cursor[dst[e]], 1);
    csr_src[pos] = src[e];
}

// ---------------------------------------------------------------------------
// Fused per-node attention kernel. One wave per dst node.
// Pass B: branch-free batches of 16 pipelined gathers (16 loads in flight).
// ---------------------------------------------------------------------------
template <bool RELU>
__global__ __launch_bounds__(256) void gat_node_kernel(
    const int* __restrict__ row_off, const int* __restrict__ csr_src,
    const float* __restrict__ s_src, const float* __restrict__ s_dst,
    const float* __restrict__ h, const float* __restrict__ b,
    float* __restrict__ out, int n)
{
    int row = blockIdx.x * 4 + (threadIdx.x >> 6);
    int lane = threadIdx.x & 63;
    if (row >= n) return;

    int beg = row_off[row], end = row_off[row + 1];
    int deg = end - beg;
    float sd = s_dst[row];
    float self_logit = leaky(s_src[row] + sd);

    // self h row: issue early
    float hself = h[(size_t)row * 64 + lane];

    // pass A: per-lane edge + strided tail -> wave max
    int   mysrc   = 0;                    // lane >= deg: points at row 0 (hot, harmless)
    float mylogit = -INFINITY;            // -> w64 = 0 for invalid lanes
    if (lane < deg) {
        mysrc = csr_src[beg + lane];
        mylogit = leaky(s_src[mysrc] + sd);
    }
    float mx = fmaxf(self_logit, mylogit);
    for (int e = beg + 64 + lane; e < end; e += 64) {
        int s = csr_src[e];
        mx = fmaxf(mx, leaky(s_src[s] + sd));
    }
    #pragma unroll
    for (int off = 32; off; off >>= 1)
        mx = fmaxf(mx, __shfl_xor(mx, off, 64));

    // vectorized weights: ONE v_exp covers the wave's 64 edges
    float w64 = __expf(mylogit - mx);
    float den = w64;
    #pragma unroll
    for (int off = 32; off; off >>= 1)
        den += __shfl_xor(den, off, 64);
    float wself = __expf(self_logit - mx);
    den += wself;

    float acc = wself * hself;

    // pass B: branch-free 16-deep pipelined gather batches
    int d0 = deg < 64 ? deg : 64;
    int nb = (d0 + 15) & ~15;             // round up; extra lanes have w=0
    for (int i = 0; i < nb; i += 16) {
        float hv[16];
        #pragma unroll
        for (int j = 0; j < 16; ++j) {
            int s = __builtin_amdgcn_readlane(mysrc, i + j);
            hv[j] = h[(size_t)s * 64 + lane];
        }
        #pragma unroll
        for (int j = 0; j < 16; ++j)
            acc += readlane_f(w64, i + j) * hv[j];
    }
    // rare tail: deg > 64
    for (int e = beg + 64; e < end; ++e) {
        int s = csr_src[e];
        float w = __expf(leaky(s_src[s] + sd) - mx);
        den += w;
        acc += w * h[(size_t)s * 64 + lane];
    }

    float v = acc / den + b[lane];
    if (RELU) v = fmaxf(v, 0.f);
    out[(size_t)row * 64 + lane] = v;
}

// ---------------------------------------------------------------------------
extern "C" void kernel_launch(void* const* d_in, const int* in_sizes, int n_in,
                              void* d_out, int out_size, void* d_ws, size_t ws_size,
                              hipStream_t stream) {
    const float* x   = (const float*)d_in[0];
    const int*   ei  = (const int*)d_in[1];
    const float* W1  = (const float*)d_in[2];
    const float* a1s = (const float*)d_in[3];
    const float* a1d = (const float*)d_in[4];
    const float* b1  = (const float*)d_in[5];
    const float* W2  = (const float*)d_in[6];
    const float* a2s = (const float*)d_in[7];
    const float* a2d = (const float*)d_in[8];
    const float* b2  = (const float*)d_in[9];
    float* out = (float*)d_out;

    const int* src = ei;
    const int* dst = ei + N_EDGES;

    char* p = (char*)d_ws;
    float* h    = (float*)p;            p += (size_t)N_NODES * 64 * 4;
    float* ssrc = (float*)p;            p += (size_t)N_NODES * 4;
    float* sdst = (float*)p;            p += (size_t)N_NODES * 4;
    int* row_off = (int*)p;             p += (size_t)(N_NODES + 1) * 4;
    int* cursor  = (int*)p;             p += (size_t)N_NODES * 4;
    int* bsum    = (int*)p;             p += 256 * 4;
    int* csr_src = (int*)p;             p += (size_t)N_EDGES * 4;

    dim3 blk(256);
    int gemm_blocks   = (N_NODES + 63) / 64;
    int node_blocks   = (N_NODES + 3) / 4;
    int edge_blocks_t = (N_EDGES + 255) / 256;
    int scan_blocks   = (N_NODES + 255) / 256;

    // ---- CSR build ----
    hipMemsetAsync(cursor, 0, (size_t)N_NODES * 4, stream);   // cursor doubles as counts
    count_kernel<<<edge_blocks_t, blk, 0, stream>>>(dst, cursor);
    scan1_kernel<<<scan_blocks, blk, 0, stream>>>(cursor, row_off, bsum, N_NODES);
    scan2_kernel<<<1, blk, 0, stream>>>(bsum, scan_blocks);
    scan3_kernel<<<scan_blocks, blk, 0, stream>>>(row_off, bsum, cursor, N_NODES);
    scatter_kernel<<<edge_blocks_t, blk, 0, stream>>>(src, dst, cursor, csr_src);

    // ---- layer 1 ----
    gat_gemm_kernel<128><<<gemm_blocks, blk, 0, stream>>>(x, W1, a1s, a1d, h, ssrc, sdst, N_NODES);
    gat_node_kernel<true><<<node_blocks, blk, 0, stream>>>(row_off, csr_src, ssrc, sdst, h, b1, out, N_NODES);

    // ---- layer 2 ----
    gat_gemm_kernel<64><<<gemm_blocks, blk, 0, stream>>>(out, W2, a2s, a2d, h, ssrc, sdst, N_NODES);
    gat_node_kernel<false><<<node_blocks, blk, 0, stream>>>(row_off, csr_src, ssrc, sdst, h, b2, out, N_NODES);
}

// Round 6
// 171.105 us; speedup vs baseline: 4.2295x; 1.2247x over previous
//
#include <hip/hip_runtime.h>

#define N_NODES 50000
#define N_EDGES 800000
#define NEG_SLOPE 0.2f

__device__ __forceinline__ float leaky(float x) { return x >= 0.f ? x : NEG_SLOPE * x; }
__device__ __forceinline__ float readlane_f(float v, int i) {
    return __uint_as_float(__builtin_amdgcn_readlane(__float_as_uint(v), i));
}

// ---------------------------------------------------------------------------
// Register-tiled GEMM + attention scores: h = x@W (W: [K,64] row-major),
// s_src = h@a_src, s_dst = h@a_dst.  64x64 tile, BK=32, 4x4 per thread.
// ---------------------------------------------------------------------------
template <int K>
__global__ __launch_bounds__(256) void gat_gemm_kernel(
    const float* __restrict__ x, const float* __restrict__ W,
    const float* __restrict__ a_src, const float* __restrict__ a_dst,
    float* __restrict__ h, float* __restrict__ s_src, float* __restrict__ s_dst,
    int n)
{
    constexpr int BK = 32;
    __shared__ float Wl[BK][64];
    __shared__ float xt[BK][68];
    __shared__ float asl[64], adl[64];

    int tid = threadIdx.x;
    if (tid < 64) { asl[tid] = a_src[tid]; adl[tid] = a_dst[tid]; }
    int tx = tid & 15, ty = tid >> 4;
    int row0 = blockIdx.x * 64;

    float acc[4][4] = {};

    for (int k0 = 0; k0 < K; k0 += BK) {
        __syncthreads();
        {
            const float4* Wg = (const float4*)&W[(size_t)k0 * 64];
            float4* Ws = (float4*)&Wl[0][0];
            Ws[tid]       = Wg[tid];
            Ws[tid + 256] = Wg[tid + 256];
        }
        #pragma unroll
        for (int it = 0; it < 2; ++it) {
            int idx = tid + it * 256;
            int r = idx >> 3, kq = idx & 7;
            int grow = row0 + r;
            float4 v = (grow < n) ? *(const float4*)&x[(size_t)grow * K + k0 + kq * 4]
                                  : make_float4(0.f, 0.f, 0.f, 0.f);
            xt[kq * 4 + 0][r] = v.x;
            xt[kq * 4 + 1][r] = v.y;
            xt[kq * 4 + 2][r] = v.z;
            xt[kq * 4 + 3][r] = v.w;
        }
        __syncthreads();

        #pragma unroll
        for (int kk = 0; kk < BK; ++kk) {
            float4 wv = *(const float4*)&Wl[kk][tx * 4];
            float4 xv = *(const float4*)&xt[kk][ty * 4];
            acc[0][0] += xv.x * wv.x; acc[0][1] += xv.x * wv.y; acc[0][2] += xv.x * wv.z; acc[0][3] += xv.x * wv.w;
            acc[1][0] += xv.y * wv.x; acc[1][1] += xv.y * wv.y; acc[1][2] += xv.y * wv.z; acc[1][3] += xv.y * wv.w;
            acc[2][0] += xv.z * wv.x; acc[2][1] += xv.z * wv.y; acc[2][2] += xv.z * wv.z; acc[2][3] += xv.z * wv.w;
            acc[3][0] += xv.w * wv.x; acc[3][1] += xv.w * wv.y; acc[3][2] += xv.w * wv.z; acc[3][3] += xv.w * wv.w;
        }
    }

    #pragma unroll
    for (int i = 0; i < 4; ++i) {
        int grow = row0 + ty * 4 + i;
        if (grow < n) {
            float4 o = make_float4(acc[i][0], acc[i][1], acc[i][2], acc[i][3]);
            *(float4*)&h[(size_t)grow * 64 + tx * 4] = o;
        }
        float s1 = acc[i][0] * asl[tx*4+0] + acc[i][1] * asl[tx*4+1]
                 + acc[i][2] * asl[tx*4+2] + acc[i][3] * asl[tx*4+3];
        float s2 = acc[i][0] * adl[tx*4+0] + acc[i][1] * adl[tx*4+1]
                 + acc[i][2] * adl[tx*4+2] + acc[i][3] * adl[tx*4+3];
        #pragma unroll
        for (int m = 1; m < 16; m <<= 1) {
            s1 += __shfl_xor(s1, m, 64);
            s2 += __shfl_xor(s2, m, 64);
        }
        if (tx == 0 && grow < n) { s_src[grow] = s1; s_dst[grow] = s2; }
    }
}

// ---------------------------------------------------------------------------
// CSR build: count(+rank) -> scan -> atomic-free scatter
// ---------------------------------------------------------------------------
__global__ __launch_bounds__(256) void count_rank_kernel(
    const int* __restrict__ dst, int* __restrict__ counts, int* __restrict__ rank)
{
    int e = blockIdx.x * 256 + threadIdx.x;
    if (e >= N_EDGES) return;
    rank[e] = atomicAdd(&counts[dst[e]], 1);   // rank within dst segment
}

__global__ __launch_bounds__(256) void scan1_kernel(
    const int* __restrict__ counts, int* __restrict__ row_off,
    int* __restrict__ bsum, int n)
{
    __shared__ int tmp[256];
    int tid = threadIdx.x;
    int i = blockIdx.x * 256 + tid;
    int v = (i < n) ? counts[i] : 0;
    tmp[tid] = v; __syncthreads();
    for (int off = 1; off < 256; off <<= 1) {
        int add = (tid >= off) ? tmp[tid - off] : 0;
        __syncthreads();
        tmp[tid] += add;
        __syncthreads();
    }
    if (i < n) row_off[i] = tmp[tid] - v;
    if (tid == 255) bsum[blockIdx.x] = tmp[255];
}

__global__ __launch_bounds__(256) void scan2_kernel(int* __restrict__ bsum, int nb)
{
    __shared__ int tmp[256];
    int tid = threadIdx.x;
    int v = (tid < nb) ? bsum[tid] : 0;
    tmp[tid] = v; __syncthreads();
    for (int off = 1; off < 256; off <<= 1) {
        int add = (tid >= off) ? tmp[tid - off] : 0;
        __syncthreads();
        tmp[tid] += add;
        __syncthreads();
    }
    if (tid < nb) bsum[tid] = tmp[tid] - v;
}

__global__ __launch_bounds__(256) void scan3_kernel(
    int* __restrict__ row_off, const int* __restrict__ bsum, int n)
{
    int i = blockIdx.x * 256 + threadIdx.x;
    if (i < n) row_off[i] += bsum[blockIdx.x];
    if (i == 0) row_off[n] = N_EDGES;
}

// atomic-free: position precomputed, store is fire-and-forget
__global__ __launch_bounds__(256) void scatter_kernel(
    const int* __restrict__ src, const int* __restrict__ dst,
    const int* __restrict__ row_off, const int* __restrict__ rank,
    int* __restrict__ csr_src)
{
    int e = blockIdx.x * 256 + threadIdx.x;
    if (e >= N_EDGES) return;
    csr_src[row_off[dst[e]] + rank[e]] = src[e];
}

// ---------------------------------------------------------------------------
// Fused per-node attention kernel. One wave per dst node.
// Pass B: branch-free batches of 16 pipelined gathers (16 loads in flight).
// ---------------------------------------------------------------------------
template <bool RELU>
__global__ __launch_bounds__(256) void gat_node_kernel(
    const int* __restrict__ row_off, const int* __restrict__ csr_src,
    const float* __restrict__ s_src, const float* __restrict__ s_dst,
    const float* __restrict__ h, const float* __restrict__ b,
    float* __restrict__ out, int n)
{
    int row = blockIdx.x * 4 + (threadIdx.x >> 6);
    int lane = threadIdx.x & 63;
    if (row >= n) return;

    int beg = row_off[row], end = row_off[row + 1];
    int deg = end - beg;
    float sd = s_dst[row];
    float self_logit = leaky(s_src[row] + sd);

    float hself = h[(size_t)row * 64 + lane];

    int   mysrc   = 0;
    float mylogit = -INFINITY;
    if (lane < deg) {
        mysrc = csr_src[beg + lane];
        mylogit = leaky(s_src[mysrc] + sd);
    }
    float mx = fmaxf(self_logit, mylogit);
    for (int e = beg + 64 + lane; e < end; e += 64) {
        int s = csr_src[e];
        mx = fmaxf(mx, leaky(s_src[s] + sd));
    }
    #pragma unroll
    for (int off = 32; off; off >>= 1)
        mx = fmaxf(mx, __shfl_xor(mx, off, 64));

    float w64 = __expf(mylogit - mx);
    float den = w64;
    #pragma unroll
    for (int off = 32; off; off >>= 1)
        den += __shfl_xor(den, off, 64);
    float wself = __expf(self_logit - mx);
    den += wself;

    float acc = wself * hself;

    int d0 = deg < 64 ? deg : 64;
    int nb = (d0 + 15) & ~15;
    for (int i = 0; i < nb; i += 16) {
        float hv[16];
        #pragma unroll
        for (int j = 0; j < 16; ++j) {
            int s = __builtin_amdgcn_readlane(mysrc, i + j);
            hv[j] = h[(size_t)s * 64 + lane];
        }
        #pragma unroll
        for (int j = 0; j < 16; ++j)
            acc += readlane_f(w64, i + j) * hv[j];
    }
    for (int e = beg + 64; e < end; ++e) {
        int s = csr_src[e];
        float w = __expf(leaky(s_src[s] + sd) - mx);
        den += w;
        acc += w * h[(size_t)s * 64 + lane];
    }

    float v = acc / den + b[lane];
    if (RELU) v = fmaxf(v, 0.f);
    out[(size_t)row * 64 + lane] = v;
}

// ---------------------------------------------------------------------------
extern "C" void kernel_launch(void* const* d_in, const int* in_sizes, int n_in,
                              void* d_out, int out_size, void* d_ws, size_t ws_size,
                              hipStream_t stream) {
    const float* x   = (const float*)d_in[0];
    const int*   ei  = (const int*)d_in[1];
    const float* W1  = (const float*)d_in[2];
    const float* a1s = (const float*)d_in[3];
    const float* a1d = (const float*)d_in[4];
    const float* b1  = (const float*)d_in[5];
    const float* W2  = (const float*)d_in[6];
    const float* a2s = (const float*)d_in[7];
    const float* a2d = (const float*)d_in[8];
    const float* b2  = (const float*)d_in[9];
    float* out = (float*)d_out;

    const int* src = ei;
    const int* dst = ei + N_EDGES;

    char* p = (char*)d_ws;
    float* h    = (float*)p;            p += (size_t)N_NODES * 64 * 4;
    float* ssrc = (float*)p;            p += (size_t)N_NODES * 4;
    float* sdst = (float*)p;            p += (size_t)N_NODES * 4;
    int* row_off = (int*)p;             p += (size_t)(N_NODES + 1) * 4;
    int* counts  = (int*)p;             p += (size_t)N_NODES * 4;
    int* bsum    = (int*)p;             p += 256 * 4;
    int* csr_src = (int*)p;             p += (size_t)N_EDGES * 4;

    int* rank = (int*)h;   // h (12.8 MB) is dead until gemm1; rank needs 3.2 MB

    dim3 blk(256);
    int gemm_blocks   = (N_NODES + 63) / 64;
    int node_blocks   = (N_NODES + 3) / 4;
    int edge_blocks_t = (N_EDGES + 255) / 256;
    int scan_blocks   = (N_NODES + 255) / 256;

    // ---- CSR build (atomic-free scatter via precomputed ranks) ----
    hipMemsetAsync(counts, 0, (size_t)N_NODES * 4, stream);
    count_rank_kernel<<<edge_blocks_t, blk, 0, stream>>>(dst, counts, rank);
    scan1_kernel<<<scan_blocks, blk, 0, stream>>>(counts, row_off, bsum, N_NODES);
    scan2_kernel<<<1, blk, 0, stream>>>(bsum, scan_blocks);
    scan3_kernel<<<scan_blocks, blk, 0, stream>>>(row_off, bsum, N_NODES);
    scatter_kernel<<<edge_blocks_t, blk, 0, stream>>>(src, dst, row_off, rank, csr_src);

    // ---- layer 1 ----
    gat_gemm_kernel<128><<<gemm_blocks, blk, 0, stream>>>(x, W1, a1s, a1d, h, ssrc, sdst, N_NODES);
    gat_node_kernel<true><<<node_blocks, blk, 0, stream>>>(row_off, csr_src, ssrc, sdst, h, b1, out, N_NODES);

    // ---- layer 2 ----
    gat_gemm_kernel<64><<<gemm_blocks, blk, 0, stream>>>(out, W2, a2s, a2d, h, ssrc, sdst, N_NODES);
    gat_node_kernel<false><<<node_blocks, blk, 0, stream>>>(row_off, csr_src, ssrc, sdst, h, b2, out, N_NODES);
}